// Round 1
// baseline (88.765 us; speedup 1.0000x reference)
//
#include <hip/hip_runtime.h>

#define NCELL 1024
#define BATCH 16

// ---------------------------------------------------------------------------
// Kernel 1: one block (64 threads, 1 wave) per batch. Runs the A* scan until
// this batch first selects its goal (provably equivalent to the reference's
// coupled scan; see analysis). State lives in LDS. Writes:
//   - hist map (final state) directly to out[b*1024 + c]
//   - parents (u16) + s_b (first-solve step) + goalidx to workspace
// ---------------------------------------------------------------------------
__global__ __launch_bounds__(64) void astar_main(
    const float* __restrict__ cost_g,
    const float* __restrict__ start_g,
    const float* __restrict__ goal_g,
    const float* __restrict__ obst_g,
    float* __restrict__ out,
    int* __restrict__ meta,
    unsigned short* __restrict__ wpar)
{
    const int b = blockIdx.x;
    const int lane = threadIdx.x;
    const int base = b * NCELL;
    const float inv = 0.17677669529663687f;  // 1/sqrt(32) rounded to f32

    __shared__ float s_fexp[NCELL];
    __shared__ float s_g[NCELL];
    __shared__ float s_cost[NCELL];
    __shared__ float s_h[NCELL];
    __shared__ unsigned char s_open[NCELL];
    __shared__ unsigned char s_hist[NCELL];
    __shared__ unsigned char s_obst[NCELL];
    __shared__ unsigned short s_par[NCELL];
    __shared__ int s_goal;

    // goal index (one-hot input)
    for (int c = lane; c < NCELL; c += 64)
        if (goal_g[base + c] != 0.0f) s_goal = c;
    __syncthreads();
    const int goalidx = s_goal;
    const float gyf = (float)(goalidx >> 5);
    const float gxf = (float)(goalidx & 31);

    // init state + heuristic (bit-exact vs reference: all args exact ints,
    // sqrtf correctly rounded, __f*_rn blocks FMA contraction)
    for (int c = lane; c < NCELL; c += 64) {
        float costv  = cost_g[base + c];
        float startv = start_g[base + c];
        s_cost[c] = costv;
        s_open[c] = (startv != 0.0f) ? 1 : 0;
        s_hist[c] = 0;
        s_obst[c] = (obst_g[base + c] != 0.0f) ? 1 : 0;
        s_g[c]    = 0.0f;
        s_par[c]  = (unsigned short)goalidx;
        float dy = fabsf((float)(c >> 5) - gyf);
        float dx = fabsf((float)(c & 31) - gxf);
        float hb  = __fsub_rn(__fadd_rn(dy, dx), fminf(dy, dx)); // sum - min = Chebyshev
        float euc = sqrtf(__fadd_rn(__fmul_rn(dy, dy), __fmul_rn(dx, dx)));
        float h   = __fadd_rn(hb, __fmul_rn(0.001f, euc));
        s_h[c] = h;
        float f = __fadd_rn(__fmul_rn(0.5f, 0.0f), __fmul_rn(0.5f, h)); // g = 0
        float e = expf(__fmul_rn(-f, inv));
        s_fexp[c] = (startv != 0.0f) ? e : 0.0f;
    }
    __syncthreads();

    int sb = NCELL - 1;               // reference t contribution if never solved
    const int c0 = lane << 4;         // each lane owns 16 contiguous cells
    for (int t = 0; t < NCELL; ++t) {
        // ---- argmax over f_exp (np.argmax semantics: first max wins) ----
        float v[16];
        ((float4*)v)[0] = ((const float4*)(s_fexp + c0))[0];
        ((float4*)v)[1] = ((const float4*)(s_fexp + c0))[1];
        ((float4*)v)[2] = ((const float4*)(s_fexp + c0))[2];
        ((float4*)v)[3] = ((const float4*)(s_fexp + c0))[3];
        float bv = v[0]; int bi = 0;
        #pragma unroll
        for (int i = 1; i < 16; ++i)
            if (v[i] > bv) { bv = v[i]; bi = i; }   // strict > keeps first index
        // key: [fexp bits | 1023-idx]  -> u64 max == (max val, min idx on tie)
        unsigned long long key =
            (((unsigned long long)__float_as_uint(bv)) << 10) |
            (unsigned long long)(1023 - (c0 + bi));
        #pragma unroll
        for (int m = 1; m < 64; m <<= 1) {
            unsigned long long ok = __shfl_xor(key, m, 64);
            if (ok > key) key = ok;
        }
        const int sel = 1023 - (int)(key & 1023ull);
        const bool solved = (sel == goalidx);

        // g2 value broadcast to the 8 neighbors (single f32 add, ref order)
        const float g2v = __fadd_rn(s_g[sel], s_cost[sel]);

        // selected-cell updates (hist always; open/fexp cleared only if unsolved)
        if (lane == 0) {
            s_hist[sel] = 1;
            if (!solved) { s_open[sel] = 0; s_fexp[sel] = 0.0f; }
        }
        // neighbor updates: lanes 0..8 = 3x3 stencil minus center
        if (lane < 9 && lane != 4) {
            const int dr = lane / 3 - 1, dc = lane % 3 - 1;
            const int nr = (sel >> 5) + dr, nc = (sel & 31) + dc;
            if (nr >= 0 && nr < 32 && nc >= 0 && nc < 32) {
                const int p = (nr << 5) + nc;
                const bool o  = s_open[p] != 0;
                const bool hs = s_hist[p] != 0;
                if (s_obst[p] && ((!o && !hs) || (o && (s_g[p] > g2v)))) {
                    s_g[p]   = g2v;
                    s_par[p] = (unsigned short)sel;
                    s_open[p] = 1;
                    float f = __fadd_rn(__fmul_rn(0.5f, g2v),
                                        __fmul_rn(0.5f, s_h[p]));
                    s_fexp[p] = expf(__fmul_rn(-f, inv));
                }
            }
        }
        if (solved) { sb = t; break; }   // state static for all later steps
    }

    // outputs: hist (final), parents, per-batch solve step + goal idx
    for (int c = lane; c < NCELL; c += 64) {
        out[base + c] = s_hist[c] ? 1.0f : 0.0f;
        wpar[base + c] = s_par[c];
    }
    if (lane == 0) { meta[b] = sb; meta[BATCH + b] = goalidx; }
}

// ---------------------------------------------------------------------------
// Kernel 2: backtrack. T = max_b s_b (== reference t_fin). Walk the parent
// chain from the goal, marking cells; early-exit on a revisited marked cell
// (identical set to the reference's T-iteration fori_loop).
// ---------------------------------------------------------------------------
__global__ __launch_bounds__(64) void astar_bt(
    const int* __restrict__ meta,
    const unsigned short* __restrict__ wpar,
    float* __restrict__ out)
{
    const int b = blockIdx.x;
    const int lane = threadIdx.x;
    __shared__ unsigned short lpar[NCELL];
    __shared__ unsigned int pmask[32];

    for (int c = lane; c < NCELL; c += 64)
        lpar[c] = wpar[b * NCELL + c];
    if (lane < 32) pmask[lane] = 0u;
    int T = 0;
    #pragma unroll
    for (int i = 0; i < BATCH; ++i) {
        int s = meta[i];
        T = (s > T) ? s : T;
    }
    const int goalidx = meta[BATCH + b];
    __syncthreads();

    if (lane == 0) {
        pmask[goalidx >> 5] |= (1u << (goalidx & 31));   // path init = goal one-hot
        int loc = lpar[goalidx];                          // loc0 = parents[goal]
        for (int it = 0; it < T; ++it) {
            unsigned int w   = pmask[loc >> 5];
            unsigned int bit = 1u << (loc & 31);
            if (w & bit) break;          // orbit from here already marked
            pmask[loc >> 5] = w | bit;
            loc = lpar[loc];
        }
    }
    __syncthreads();

    for (int c = lane; c < NCELL; c += 64)
        out[BATCH * NCELL + b * NCELL + c] =
            ((pmask[c >> 5] >> (c & 31)) & 1u) ? 1.0f : 0.0f;
}

extern "C" void kernel_launch(void* const* d_in, const int* in_sizes, int n_in,
                              void* d_out, int out_size, void* d_ws, size_t ws_size,
                              hipStream_t stream)
{
    const float* cost  = (const float*)d_in[0];
    const float* start = (const float*)d_in[1];
    const float* goal  = (const float*)d_in[2];
    // d_in[3] = heuristic_maps: unused by the reference
    const float* obst  = (const float*)d_in[4];
    float* out = (float*)d_out;

    int* meta = (int*)d_ws;                                        // 32 ints
    unsigned short* wpar = (unsigned short*)((char*)d_ws + 256);   // 16*1024 u16

    astar_main<<<BATCH, 64, 0, stream>>>(cost, start, goal, obst, out, meta, wpar);
    astar_bt<<<BATCH, 64, 0, stream>>>(meta, wpar, out);
}

// Round 2
// 86.598 us; speedup vs baseline: 1.0250x; 1.0250x over previous
//
#include <hip/hip_runtime.h>

#define NCELL 1024
#define BATCH 16

// v = max(v, dpp_perm(v)); invalid lanes receive their own value (old=v).
template <int CTRL>
__device__ __forceinline__ float dppmaxf(float v) {
    int r = __builtin_amdgcn_update_dpp(__float_as_int(v), __float_as_int(v),
                                        CTRL, 0xF, 0xF, false);
    return fmaxf(v, __int_as_float(r));
}

// ---------------------------------------------------------------------------
// One block (1 wave, 64 lanes) per batch: full A* scan + fused backtrack.
// Equivalence to the coupled reference scan: batches interact only through
// `done`; a batch that solves at step s_b provably re-selects its goal every
// later step (new/updated cells have f >= f_goal + 0.55), so its state is
// static after s_b and t_fin = max_b s_b. Backtrack: the parent chain
// goal->...->start has length <= s_b <= T and parents[start] = goal (marked),
// so walk-until-marked == the reference's T-iteration loop.
// ---------------------------------------------------------------------------
__global__ __launch_bounds__(64) void astar_fused(
    const float* __restrict__ cost_g,
    const float* __restrict__ start_g,
    const float* __restrict__ goal_g,
    const float* __restrict__ obst_g,
    float* __restrict__ out)
{
    const int b = blockIdx.x;
    const int lane = threadIdx.x;
    const int base = b * NCELL;
    const float inv = 0.17677669529663687f;  // 1/sqrt(32) rounded to f32

    __shared__ float  s_fexp[NCELL];
    __shared__ float2 s_gc[NCELL];           // {g, cost}
    __shared__ float  s_h[NCELL];
    __shared__ unsigned int s_flags[NCELL];  // bit0 open, bit1 hist, bit2 obst
    __shared__ unsigned short s_par[NCELL];
    __shared__ unsigned int pmask[32];
    __shared__ int s_goal;

    // goal index (one-hot input)
    for (int c = lane; c < NCELL; c += 64)
        if (goal_g[base + c] != 0.0f) s_goal = c;
    __syncthreads();
    const int goalidx = s_goal;
    const float gyf = (float)(goalidx >> 5);
    const float gxf = (float)(goalidx & 31);

    // init (bit-exact vs reference: exact ints, sqrtf correctly rounded,
    // __f*_rn blocks FMA contraction)
    for (int c = lane; c < NCELL; c += 64) {
        float costv  = cost_g[base + c];
        float startv = start_g[base + c];
        unsigned int fl = 0;
        if (startv != 0.0f)          fl |= 1u;
        if (obst_g[base + c] != 0.0f) fl |= 4u;
        s_flags[c] = fl;
        s_gc[c] = make_float2(0.0f, costv);
        s_par[c] = (unsigned short)goalidx;
        float dy = fabsf((float)(c >> 5) - gyf);
        float dx = fabsf((float)(c & 31) - gxf);
        float hb  = __fsub_rn(__fadd_rn(dy, dx), fminf(dy, dx));
        float euc = sqrtf(__fadd_rn(__fmul_rn(dy, dy), __fmul_rn(dx, dx)));
        float h   = __fadd_rn(hb, __fmul_rn(0.001f, euc));
        s_h[c] = h;
        float f = __fmul_rn(0.5f, h);               // 0.5*g(=0) + 0.5*h
        float e = expf(__fmul_rn(-f, inv));
        s_fexp[c] = (startv != 0.0f) ? e : 0.0f;
    }
    __syncthreads();

    const int c0 = lane << 4;  // each lane owns 16 contiguous cells
    for (int t = 0; t < NCELL; ++t) {
        // ---- per-lane first-max over 16 cells (tree, compile-time idx) ----
        float v[16];
        ((float4*)v)[0] = ((const float4*)(s_fexp + c0))[0];
        ((float4*)v)[1] = ((const float4*)(s_fexp + c0))[1];
        ((float4*)v)[2] = ((const float4*)(s_fexp + c0))[2];
        ((float4*)v)[3] = ((const float4*)(s_fexp + c0))[3];
        float m[8]; int j[8];
        #pragma unroll
        for (int i = 0; i < 8; ++i) {
            bool r = v[2*i+1] > v[2*i];
            m[i] = r ? v[2*i+1] : v[2*i];
            j[i] = r ? 2*i+1 : 2*i;
        }
        #pragma unroll
        for (int i = 0; i < 4; ++i) {
            bool r = m[2*i+1] > m[2*i];
            m[i] = r ? m[2*i+1] : m[2*i];
            j[i] = r ? j[2*i+1] : j[2*i];
        }
        #pragma unroll
        for (int i = 0; i < 2; ++i) {
            bool r = m[2*i+1] > m[2*i];
            m[i] = r ? m[2*i+1] : m[2*i];
            j[i] = r ? j[2*i+1] : j[2*i];
        }
        bool rr = m[1] > m[0];
        float bv = rr ? m[1] : m[0];
        int   bi = rr ? j[1] : j[0];

        // ---- wave max via DPP (VALU-only), then lowest-lane tie-break ----
        float w = bv;
        w = dppmaxf<0x111>(w);   // row_shr:1
        w = dppmaxf<0x112>(w);   // row_shr:2
        w = dppmaxf<0x114>(w);   // row_shr:4
        w = dppmaxf<0x118>(w);   // row_shr:8
        w = dppmaxf<0x142>(w);   // row_bcast:15
        w = dppmaxf<0x143>(w);   // row_bcast:31
        float vmax = __int_as_float(
            __builtin_amdgcn_readlane(__float_as_int(w), 63));
        unsigned long long msk = __ballot(bv == vmax);
        int winner = (int)__builtin_ctzll(msk);     // lowest lane = lowest idx
        int sel = __builtin_amdgcn_readlane(c0 + bi, winner);
        const bool solved = (sel == goalidx);

        // g2 value broadcast to the 8 neighbors (one b64 read, ref add order)
        float2 gc = s_gc[sel];
        const float g2v = __fadd_rn(gc.x, gc.y);

        // selected-cell update (lane 9 runs parallel to neighbor lanes 0-8)
        if (lane == 9) {
            unsigned int fl = s_flags[sel];
            fl |= 2u;                                  // hist
            if (!solved) { fl &= ~1u; s_fexp[sel] = 0.0f; }  // close
            s_flags[sel] = fl;
        }
        // neighbor updates: lanes 0..8 = 3x3 stencil minus center
        if (lane < 9 && lane != 4) {
            const int dr = lane / 3 - 1, dc = lane % 3 - 1;
            const int nr = (sel >> 5) + dr, nc = (sel & 31) + dc;
            if (nr >= 0 && nr < 32 && nc >= 0 && nc < 32) {
                const int p = (nr << 5) + nc;
                unsigned int fl = s_flags[p];
                float gp = s_gc[p].x;
                bool o  = (fl & 1u) != 0;
                bool hs = (fl & 2u) != 0;
                if ((fl & 4u) && ((!o && !hs) || (o && gp > g2v))) {
                    s_gc[p].x = g2v;
                    s_par[p] = (unsigned short)sel;
                    s_flags[p] = fl | 1u;
                    float f = __fadd_rn(__fmul_rn(0.5f, g2v),
                                        __fmul_rn(0.5f, s_h[p]));
                    s_fexp[p] = expf(__fmul_rn(-f, inv));
                }
            }
        }
        if (solved) break;   // state static for all later steps
    }

    // ---- fused backtrack (per-batch; no cross-block T needed) ----
    if (lane < 32) pmask[lane] = 0u;
    if (lane == 0) {
        pmask[goalidx >> 5] |= 1u << (goalidx & 31);
        int loc = s_par[goalidx];
        for (int it = 0; it < NCELL; ++it) {
            unsigned int wd  = pmask[loc >> 5];
            unsigned int bit = 1u << (loc & 31);
            if (wd & bit) break;
            pmask[loc >> 5] = wd | bit;
            loc = s_par[loc];
        }
    }

    // outputs: hist then path
    for (int c = lane; c < NCELL; c += 64) {
        out[base + c] = (s_flags[c] & 2u) ? 1.0f : 0.0f;
        out[BATCH * NCELL + base + c] =
            ((pmask[c >> 5] >> (c & 31)) & 1u) ? 1.0f : 0.0f;
    }
}

extern "C" void kernel_launch(void* const* d_in, const int* in_sizes, int n_in,
                              void* d_out, int out_size, void* d_ws, size_t ws_size,
                              hipStream_t stream)
{
    const float* cost  = (const float*)d_in[0];
    const float* start = (const float*)d_in[1];
    const float* goal  = (const float*)d_in[2];
    // d_in[3] = heuristic_maps: unused by the reference
    const float* obst  = (const float*)d_in[4];
    float* out = (float*)d_out;

    astar_fused<<<BATCH, 64, 0, stream>>>(cost, start, goal, obst, out);
}